// Round 7
// baseline (145.549 us; speedup 1.0000x reference)
//
#include <hip/hip_runtime.h>
#include <math.h>

#define TS   32
#define NPIX 1024
#define DF   72      // real feature dim
#define KP   96      // padded K: 3 MFMA k-steps of 32
#define IMH  320
#define IMW  320
#define NTW  10
#define NTILE 100
#define STRIPS 16    // 4 row-tiles (64 rows) per strip

// ws layout: Fhi at 0, Sq at SQ_OFF (proven), strip partials at 64 MiB
#define F_UNITS_PER_TILE 12288           // 64 rt * 3 ks * 4 c * 16 rows
#define FHI_BYTES (NTILE * F_UNITS_PER_TILE * 16)   // 19,660,800
#define SQ_OFF    (2 * FHI_BYTES)                   // 39,321,600
#define PART_OFF  (64u << 20)                       // 67,108,864 (+26.2MB < 256MB)

#define K2LOG2E 2.0813689810056077f      // (log2 e)^2: exp(-sqrt(x)) = exp2(-sqrt(K2*x))
#define FSCALE  2.0402789f               // sqrt(2*K2LOG2E): Gram = 2*K2*<F,F>

typedef __attribute__((ext_vector_type(8))) short bf16x8;   // MFMA A/B frag
typedef __attribute__((ext_vector_type(8))) unsigned short u16x8;
typedef __attribute__((ext_vector_type(4))) float f32x4;    // MFMA C/D
typedef __attribute__((ext_vector_type(4))) __fp16 f16x4;   // 16x16x16 f16 A/B frag
typedef __attribute__((ext_vector_type(2))) __fp16 f16x2;

// ---------------- kernel A: feature build (RNE bf16, pre-scaled) + sqf ----
// Features scaled by FSCALE so Gram MFMA yields 2*K2*<F,F>; Sq = K2*|F|^2.
__global__ __launch_bounds__(256)
void nlm_feat_kernel(const float* __restrict__ img,
                     u16x8* __restrict__ Fhi, float* __restrict__ Sq)
{
    __shared__ float Ploc[3][6][36];   // padded rows [2p, 2p+6) of the tile
    __shared__ int   ofsl[KP];
    const int tid  = threadIdx.x;
    const int part = blockIdx.x;    // 0..15
    const int tile = blockIdx.y;
    const int by   = (tile / NTW) * TS;
    const int bx   = (tile % NTW) * TS;
    const float* Pf = &Ploc[0][0][0];

    for (int idx = tid; idx < 3 * 6 * 36; idx += 256) {
        int c   = idx / 216;
        int rem = idx - c * 216;
        int yl  = rem / 36;
        int x   = rem - yl * 36;
        int y   = 2 * part + yl;
        int iy  = min(max(y - 2, 0), TS - 1);
        int ix  = min(max(x - 2, 0), TS - 1);
        Ploc[c][yl][x] = img[(c * IMH + by + iy) * IMW + bx + ix];
    }
    if (tid < KP) {
        int k = tid, v = 0;
        if (k < DF) {
            int c = k / 24, o = k - c * 24;
            int kk = o + (o >= 12);
            int i = kk / 5, j = kk - (kk / 5) * 5;
            v = c * 216 + i * 36 + j;
        }
        ofsl[k] = v;
    }
    __syncthreads();

    if (tid < 64) {
        int m  = part * 64 + tid;
        int my = m >> 5, mx = m & 31;
        int ly0 = my - 2 * part;
        float s = 0.f;
        #pragma unroll
        for (int k = 0; k < 25; ++k) {
            if (k == 12) continue;
            int i = k / 5, j = k - (k / 5) * 5;
            float v0 = Ploc[0][ly0 + i][mx + j];
            float v1 = Ploc[1][ly0 + i][mx + j];
            float v2 = Ploc[2][ly0 + i][mx + j];
            s = fmaf(v0, v0, s); s = fmaf(v1, v1, s); s = fmaf(v2, v2, s);
        }
        Sq[tile * NPIX + m] = s * K2LOG2E;   // K2 * |F|^2
    }

    #pragma unroll
    for (int q = 0; q < 3; ++q) {
        int u    = part * 768 + q * 256 + tid;
        int row  = u & 15;
        int c4   = (u >> 4) & 3;
        int rks  = u >> 6;
        int ks   = rks - (rks / 3) * 3;
        int rt   = rks / 3;
        int r    = rt * 16 + row;
        int lbase = ((r >> 5) - 2 * part) * 36 + (r & 31);
        u16x8 h;
        #pragma unroll
        for (int j = 0; j < 8; ++j) {
            int k = ks * 32 + c4 * 8 + j;
            unsigned short hs = 0;
            if (k < DF) {
                float f = Pf[lbase + ofsl[k]] * FSCALE;
                unsigned int uu = __float_as_uint(f);
                hs = (unsigned short)((uu + 0x7fffu + ((uu >> 16) & 1u)) >> 16);
            }
            h[j] = hs;
        }
        Fhi[tile * F_UNITS_PER_TILE + u] = h;
    }
}

// ---------------- kernel B: symmetric triangle Gram + dual-side PV --------
// R17: each dens fragment computed ONCE (triangle j>=iw) and used for BOTH
//      output directions. n-side: wp-as-A (contracts over j-tile) into reg
//      acc. m-side: transpose via mfma(wp, I) (exact), re-pack, 2 PV vs own
//      Y-frag, ds_add scatter into block LDS acc. Halves trans+Gram work.
//      Block = strip of 4 row-tiles; k-major XCD-pinned dispatch (longest
//      strips first, 13 tiles per XCD L2-resident). Strip partials -> ws.
__global__ __launch_bounds__(256)
__attribute__((amdgpu_waves_per_eu(4, 8)))
void nlm_sym_kernel(const float* __restrict__ img,
                    const bf16x8* __restrict__ Fhi,
                    const float* __restrict__ SqK,
                    float* __restrict__ part)
{
    __shared__ __fp16 Yhi[4][1032];
    __shared__ __fp16 Ylo[4][1032];
    __shared__ float acc[NPIX][4];      // 16 KB block accumulator

    // grid 1664 = 8 XCD * 208; XCD x owns tiles {x, x+8, ...}; k-major order
    const int x    = blockIdx.x & 7;
    const int r    = blockIdx.x >> 3;       // 0..207
    const int k    = r / 13;                // strip 0..15 (long strips first)
    const int tile = x + 8 * (r - k * 13);
    if (tile >= NTILE) return;

    const int tid  = threadIdx.x;
    const int lane = tid & 63;
    const int wv   = tid >> 6;              // 0..3
    const int quad = lane >> 4;
    const int col  = lane & 15;
    const int ycol = col & 3;
    const int iw   = k * 4 + wv;            // wave's row-tile 0..63
    const int by   = (tile / NTW) * TS;
    const int bx   = (tile % NTW) * TS;

    const bf16x8* FHt = Fhi + tile * F_UNITS_PER_TILE;
    const float*  Sqt = SqK + tile * NPIX;

    for (int idx = tid; idx < 4096; idx += 256)
        ((float*)acc)[idx] = 0.f;

    // stage Y = [y0,y1,y2,1] as f16 hi + lo residual
    for (int idx = tid; idx < 1024; idx += 256) {
        int c = idx >> 8, m4 = (idx & 255) << 2;
        f32x4 v = {1.f, 1.f, 1.f, 1.f};
        if (c < 3) v = *(const f32x4*)&img[(c * IMH + by + (m4 >> 5)) * IMW + bx + (m4 & 31)];
        f16x4 h, l;
        #pragma unroll
        for (int j = 0; j < 4; ++j) {
            h[j] = (__fp16)v[j];
            l[j] = (__fp16)(v[j] - (float)h[j]);
        }
        *(f16x4*)&Yhi[c][m4] = h;
        *(f16x4*)&Ylo[c][m4] = l;
    }

    // wave-pinned: negated F_iw (Gram B), sni, identity f16 frag
    bf16x8 bN0, bN1, bN2;
    {
        bf16x8 sgn;
        #pragma unroll
        for (int j = 0; j < 8; ++j) sgn[j] = (short)0x8000;
        bN0 = FHt[(iw * 3 + 0) * 64 + lane] ^ sgn;
        bN1 = FHt[(iw * 3 + 1) * 64 + lane] ^ sgn;
        bN2 = FHt[(iw * 3 + 2) * 64 + lane] ^ sgn;
    }
    asm volatile("" : "+v"(bN0), "+v"(bN1), "+v"(bN2));
    const float sni = Sqt[iw * 16 + col];
    f16x4 idf;
    #pragma unroll
    for (int j = 0; j < 4; ++j)
        idf[j] = (__fp16)((quad * 4 + j == col) ? 1.f : 0.f);

    f32x4 Dn = {0.f, 0.f, 0.f, 0.f};    // n-side acc (hi+lo fused)

    __syncthreads();

    // wave's own Y fragment (m-side B operand), fixed
    const f16x4 bhN = *(const f16x4*)&Yhi[ycol][iw * 16 + quad * 4];
    const f16x4 blN = *(const f16x4*)&Ylo[ycol][iw * 16 + quad * 4];

#define LOADJ(j_, a0, a1, a2, sq, bh, bl)                        \
    do {                                                         \
        int _j = (j_);                                           \
        a0 = FHt[(_j * 3 + 0) * 64 + lane];                      \
        a1 = FHt[(_j * 3 + 1) * 64 + lane];                      \
        a2 = FHt[(_j * 3 + 2) * 64 + lane];                      \
        sq = *(const f32x4*)&Sqt[_j * 16 + quad * 4];            \
        bh = *(const f16x4*)&Yhi[ycol][_j * 16 + quad * 4];      \
        bl = *(const f16x4*)&Ylo[ycol][_j * 16 + quad * 4];      \
    } while (0)

#define COMPUTEJ(j_, a0, a1, a2, sq, bh, bl)                                         \
    do {                                                                             \
        int _j = (j_);                                                               \
        f32x4 C = {sq[0] + sni, sq[1] + sni, sq[2] + sni, sq[3] + sni};              \
        C = __builtin_amdgcn_mfma_f32_16x16x32_bf16(a0, bN0, C, 0, 0, 0);            \
        C = __builtin_amdgcn_mfma_f32_16x16x32_bf16(a1, bN1, C, 0, 0, 0);            \
        C = __builtin_amdgcn_mfma_f32_16x16x32_bf16(a2, bN2, C, 0, 0, 0);            \
        float d[4];                                                                  \
        _Pragma("unroll")                                                            \
        for (int i = 0; i < 4; ++i) {                                                \
            float s2 = fmaxf(C[i], 0.f);                                             \
            d[i] = __builtin_amdgcn_exp2f(-__builtin_amdgcn_sqrtf(s2));              \
        }                                                                            \
        if (_j == iw) {                                                              \
            _Pragma("unroll")                                                        \
            for (int i = 0; i < 4; ++i)                                              \
                if (quad * 4 + i == col) d[i] = 0.f;                                 \
        }                                                                            \
        f16x2 p0 = __builtin_amdgcn_cvt_pkrtz(d[0], d[1]);                           \
        f16x2 p1 = __builtin_amdgcn_cvt_pkrtz(d[2], d[3]);                           \
        f16x4 wp = __builtin_shufflevector(p0, p1, 0, 1, 2, 3);                      \
        Dn = __builtin_amdgcn_mfma_f32_16x16x16f16(wp, bh, Dn, 0, 0, 0);             \
        Dn = __builtin_amdgcn_mfma_f32_16x16x16f16(wp, bl, Dn, 0, 0, 0);             \
        if (_j != iw) {                                                              \
            f32x4 Z = {0.f, 0.f, 0.f, 0.f};                                          \
            f32x4 T = __builtin_amdgcn_mfma_f32_16x16x16f16(wp, idf, Z, 0, 0, 0);    \
            f16x2 q0 = __builtin_amdgcn_cvt_pkrtz(T[0], T[1]);                       \
            f16x2 q1 = __builtin_amdgcn_cvt_pkrtz(T[2], T[3]);                       \
            f16x4 wq = __builtin_shufflevector(q0, q1, 0, 1, 2, 3);                  \
            f32x4 D2 = __builtin_amdgcn_mfma_f32_16x16x16f16(wq, bhN, Z, 0, 0, 0);   \
            D2 = __builtin_amdgcn_mfma_f32_16x16x16f16(wq, blN, D2, 0, 0, 0);        \
            if (col < 4) {                                                           \
                atomicAdd(&acc[_j * 16 + quad * 4 + 0][col], D2[0]);                 \
                atomicAdd(&acc[_j * 16 + quad * 4 + 1][col], D2[1]);                 \
                atomicAdd(&acc[_j * 16 + quad * 4 + 2][col], D2[2]);                 \
                atomicAdd(&acc[_j * 16 + quad * 4 + 3][col], D2[3]);                 \
            }                                                                        \
        }                                                                            \
    } while (0)

    bf16x8 aA0, aA1, aA2, aB0, aB1, aB2;
    f32x4 sqA, sqB;
    f16x4 bhA, blA, bhB, blB;

    int j = iw;
    LOADJ(j, aA0, aA1, aA2, sqA, bhA, blA);
    while (j + 1 < 64) {
        LOADJ(j + 1, aB0, aB1, aB2, sqB, bhB, blB);
        COMPUTEJ(j, aA0, aA1, aA2, sqA, bhA, blA);
        if (j + 2 < 64) LOADJ(j + 2, aA0, aA1, aA2, sqA, bhA, blA);
        COMPUTEJ(j + 1, aB0, aB1, aB2, sqB, bhB, blB);
        j += 2;
    }
    if (j < 64) COMPUTEJ(j, aA0, aA1, aA2, sqA, bhA, blA);
#undef LOADJ
#undef COMPUTEJ

    __syncthreads();   // all m-side scatters done

    // merge n-side (rows disjoint per wave; Dn slot s -> row 4q+s, ch=col)
    if (col < 4) {
        #pragma unroll
        for (int s = 0; s < 4; ++s)
            acc[iw * 16 + quad * 4 + s][col] += Dn[s];
    }
    __syncthreads();

    float* P = part + (size_t)(tile * STRIPS + k) * (NPIX * 4);
    for (int idx = tid; idx < 4096; idx += 256)
        P[idx] = ((float*)acc)[idx];
}

// ---------------- kernel C: strip reduce + normalize ----------------------
__global__ __launch_bounds__(256)
void nlm_reduce_kernel(const float* __restrict__ part, float* __restrict__ out)
{
    const int bid  = blockIdx.x;            // 0..399
    const int tile = bid >> 2;
    const int p    = ((bid & 3) << 8) + threadIdx.x;   // pixel 0..1023
    const float* base = part + (size_t)tile * (STRIPS * NPIX * 4) + p * 4;
    float s0 = 0.f, s1 = 0.f, s2 = 0.f, s3 = 0.f;
    #pragma unroll
    for (int st = 0; st < STRIPS; ++st) {
        f32x4 v = *(const f32x4*)(base + st * (NPIX * 4));
        s0 += v[0]; s1 += v[1]; s2 += v[2]; s3 += v[3];
    }
    float inv = 1.f / s3;                   // ones-channel = rowsum
    int by = (tile / NTW) * TS, bx = (tile % NTW) * TS;
    int gy = by + (p >> 5), gx = bx + (p & 31);
    out[(0 * IMH + gy) * IMW + gx] = s0 * inv;
    out[(1 * IMH + gy) * IMW + gx] = s1 * inv;
    out[(2 * IMH + gy) * IMW + gx] = s2 * inv;
}

extern "C" void kernel_launch(void* const* d_in, const int* in_sizes, int n_in,
                              void* d_out, int out_size, void* d_ws, size_t ws_size,
                              hipStream_t stream) {
    const float* img = (const float*)d_in[0];
    float* out = (float*)d_out;
    char* ws = (char*)d_ws;
    u16x8* Fhi = (u16x8*)ws;
    float* Sq  = (float*)(ws + SQ_OFF);
    float* prt = (float*)(ws + PART_OFF);

    dim3 fgrid(16, NTILE);
    nlm_feat_kernel<<<fgrid, 256, 0, stream>>>(img, Fhi, Sq);
    nlm_sym_kernel<<<dim3(1664), 256, 0, stream>>>(img, (const bf16x8*)Fhi, Sq, prt);
    nlm_reduce_kernel<<<dim3(400), 256, 0, stream>>>(prt, out);
}